// Round 10
// baseline (4933.056 us; speedup 1.0000x reference)
//
#include <hip/hip_runtime.h>
#include <hip/hip_bf16.h>

#define NN   50000
#define EE   800000
#define FIN  32
#define HH   128
#define LL   4
#define NOUT 20
#define EPB  128     // edges per k_edge block
#define ETHR 512     // threads per k_edge block (8 waves)

typedef __attribute__((ext_vector_type(8))) short bf16x8;
typedef __attribute__((ext_vector_type(4))) short short4v;
typedef __attribute__((ext_vector_type(4))) float f32x4;

__device__ __forceinline__ float silu_f(float v){ return v / (1.f + __expf(-v)); }
__device__ __forceinline__ float sigm_f(float v){ return 1.f / (1.f + __expf(-v)); }

__device__ __forceinline__ short f2bf(float v){
  union { float f; unsigned u; } a; a.f = v;
  unsigned r = a.u + 0x7fff + ((a.u >> 16) & 1);
  return (short)(r >> 16);
}
__device__ __forceinline__ float bf2f(short s){
  union { unsigned u; float f; } a; a.u = ((unsigned)(unsigned short)s) << 16;
  return a.f;
}

__device__ __forceinline__ f32x4 mfma16(bf16x8 a, bf16x8 b, f32x4 c){
  return __builtin_amdgcn_mfma_f32_16x16x32_bf16(a, b, c, 0, 0, 0);
}

// ---------------------------------------------------------------------------
// A staged in LDS as bf16 hi/lo, element (e,k) at short index e*128 + (k ^ ((e&7)<<3)).
// Weights pre-transposed fragment-major bf16 hi/lo: Wp[c*128 + k] = bf16(W[k][c]).
// Split-bf16 GEMM (3-term): acc += A@W via ah*wh + ah*wl + al*wh.
// Wave tiling: 8 waves = 4 edge-groups (eg=wv&3, 32 edges) x 2 col-groups
// (cg=wv>>2, 64 cols). acc[fr][cf]: row = eg*32+fr*16+(lane>>4)*4+j,
// col = cg*64+cf*16+(lane&15). A-traffic replication 2x (was 8x).
// ---------------------------------------------------------------------------
__device__ __forceinline__ void gemm24(const short* Ah, const short* Al,
                                       const short* __restrict__ Wh,
                                       const short* __restrict__ Wl,
                                       int cl, int g, int eg, int cg,
                                       f32x4 acc[2][4])
{
  #pragma unroll
  for (int kb = 0; kb < 4; kb++) {
    const int kk = kb*32 + g*8;
    bf16x8 bh[4], bl[4];
    #pragma unroll
    for (int cf = 0; cf < 4; cf++) {
      const int wb = (cg*64 + cf*16 + cl)*HH + kk;
      bh[cf] = *(const bf16x8*)&Wh[wb];
      bl[cf] = *(const bf16x8*)&Wl[wb];
    }
    #pragma unroll
    for (int fr = 0; fr < 2; fr++) {
      const int e = eg*32 + fr*16 + cl;
      const int off = e*128 + (kk ^ ((e&7)<<3));
      const bf16x8 ah = *(const bf16x8*)&Ah[off];
      const bf16x8 al = *(const bf16x8*)&Al[off];
      #pragma unroll
      for (int cf = 0; cf < 4; cf++) {
        acc[fr][cf] = mfma16(ah, bh[cf], acc[fr][cf]);
        acc[fr][cf] = mfma16(ah, bl[cf], acc[fr][cf]);
        acc[fr][cf] = mfma16(al, bh[cf], acc[fr][cf]);
      }
    }
  }
}

// ---------------- weight prep: fp32 -> transposed bf16 hi/lo planes ----------
__global__ __launch_bounds__(256)
void k_prep(const float* __restrict__ ew1, const float* __restrict__ ew2,
            const float* __restrict__ cw1v, short* __restrict__ wph,
            short* __restrict__ wpl)
{
  const int b = blockIdx.x;          // 0..15
  const int l = b >> 2, m = b & 3;
  const float* src = (m==0) ? ew1 + (size_t)l*(2*HH+1)*HH
                   : (m==1) ? ew1 + (size_t)l*(2*HH+1)*HH + HH*HH
                   : (m==2) ? ew2 + (size_t)l*HH*HH
                            : cw1v + (size_t)l*HH*HH;
  short* dh = wph + (size_t)b*HH*HH;
  short* dl = wpl + (size_t)b*HH*HH;
  for (int idx = threadIdx.x; idx < HH*HH; idx += 256) {
    const int k = idx >> 7, c = idx & 127;
    const float v = src[idx];
    const short hh = f2bf(v);
    dh[c*HH + k] = hh;
    dl[c*HH + k] = f2bf(v - bf2f(hh));
  }
}

// ---------------- input embedding + x copy + h planes ----------------
__global__ __launch_bounds__(256)
void k_embed(const float* __restrict__ hin, const float* __restrict__ xin,
             const float* __restrict__ W, const float* __restrict__ b,
             float* __restrict__ hout, float* __restrict__ xout,
             short* __restrict__ hbi, short* __restrict__ hlo)
{
  __shared__ float wl[FIN*HH];
  const int tid = threadIdx.x;
  for (int j = tid; j < FIN*HH; j += 256) wl[j] = W[j];
  __syncthreads();
  const int c  = tid & (HH-1);
  const int no = tid >> 7;
  const int v  = blockIdx.x * 2 + no;
  if (v < NN) {
    const float* hr = hin + (size_t)v * FIN;
    float acc = b[c];
    #pragma unroll
    for (int k = 0; k < FIN; k++) acc = fmaf(hr[k], wl[k*HH + c], acc);
    hout[(size_t)v*HH + c] = acc;
    const short hh = f2bf(acc);
    hbi[(size_t)v*HH + c] = hh;
    hlo[(size_t)v*HH + c] = f2bf(acc - bf2f(hh));
    if (c < 3) xout[v*3 + c] = xin[v*3 + c];
  }
}

// ---------------- degree count ----------------
__global__ __launch_bounds__(256)
void k_count(const int* __restrict__ row, int* __restrict__ deg)
{
  const int e = blockIdx.x * 256 + threadIdx.x;
  if (e < EE) atomicAdd(&deg[row[e]], 1);
}

// ---------------- single-block exclusive prefix scan over deg ----------------
__global__ __launch_bounds__(1024)
void k_scan(const int* __restrict__ deg, int* __restrict__ offs, int* __restrict__ cursor)
{
  __shared__ int part[1024];
  const int t = threadIdx.x;
  const int base = t * 49;
  int s = 0;
  for (int i = 0; i < 49; i++) { const int idx = base + i; s += (idx < NN) ? deg[idx] : 0; }
  part[t] = s;
  __syncthreads();
  if (t == 0) { int run = 0; for (int i = 0; i < 1024; i++) { const int v = part[i]; part[i] = run; run += v; } }
  __syncthreads();
  int run = part[t];
  for (int i = 0; i < 49; i++) {
    const int idx = base + i;
    if (idx < NN) { offs[idx] = run; cursor[idx] = run; run += deg[idx]; }
  }
  if (t == 1023) offs[NN] = EE;
}

// ---------------- per-edge slot assignment ----------------
__global__ __launch_bounds__(256)
void k_pos(const int* __restrict__ row, int* __restrict__ cursor, int* __restrict__ pos)
{
  const int e = blockIdx.x * 256 + threadIdx.x;
  if (e < EE) pos[e] = atomicAdd(&cursor[row[e]], 1);
}

// ---------------- fused edge pipeline: 128 edges, 8 waves (4eg x 2cg) -------
template<bool SC>
__global__ __launch_bounds__(ETHR, 4)
void k_edge(const short* __restrict__ hbi, const short* __restrict__ hlo,
            const float* __restrict__ xbuf,
            const int* __restrict__ row, const int* __restrict__ col,
            const int* __restrict__ pos,
            const short* __restrict__ wph, const short* __restrict__ wpl, int lidx,
            const float* __restrict__ W1, const float* __restrict__ b1,
            const float* __restrict__ b2,
            const float* __restrict__ attw, const float* __restrict__ attb,
            const float* __restrict__ cb1, const float* __restrict__ cw2,
            float* __restrict__ mbuf, float* __restrict__ aggx)
{
  __shared__ short Ah[EPB*128];        // 32 KB
  __shared__ short Al[EPB*128];        // 32 KB
  __shared__ float red[2][EPB];        // 1 KB
  __shared__ float scal[EPB];
  __shared__ int   rowb[EPB];
  __shared__ int   colb[EPB];
  __shared__ int   posb[EPB];
  __shared__ float diffb[EPB][3];
  __shared__ float radb[EPB];

  const int tid  = threadIdx.x;
  const int lane = tid & 63;
  const int wv   = tid >> 6;           // 0..7
  const int cl   = lane & 15;
  const int g    = lane >> 4;
  const int eg   = wv & 3;             // edge group: rows eg*32 .. +32
  const int cg   = wv >> 2;            // col group: cols cg*64 .. +64
  const int eb   = blockIdx.x * EPB;

  const short* W1a_h = wph + (size_t)(lidx*4+0)*HH*HH;
  const short* W1a_l = wpl + (size_t)(lidx*4+0)*HH*HH;
  const short* W1b_h = wph + (size_t)(lidx*4+1)*HH*HH;
  const short* W1b_l = wpl + (size_t)(lidx*4+1)*HH*HH;
  const short* W2_h  = wph + (size_t)(lidx*4+2)*HH*HH;
  const short* W2_l  = wpl + (size_t)(lidx*4+2)*HH*HH;
  const short* C1_h  = wph + (size_t)(lidx*4+3)*HH*HH;
  const short* C1_l  = wpl + (size_t)(lidx*4+3)*HH*HH;

  // ---- phase 1: edge metadata ----
  if (tid < EPB) {
    const int r  = row[eb + tid];
    const int c2 = col[eb + tid];
    rowb[tid] = r; colb[tid] = c2;
    if (SC) posb[tid] = pos[eb + tid];
    const float dx = xbuf[r*3+0] - xbuf[c2*3+0];
    const float dy = xbuf[r*3+1] - xbuf[c2*3+1];
    const float dz = xbuf[r*3+2] - xbuf[c2*3+2];
    diffb[tid][0] = dx; diffb[tid][1] = dy; diffb[tid][2] = dz;
    radb[tid] = dx*dx + dy*dy + dz*dz;
  }
  __syncthreads();                     // 1

  // ---- phase 2: stage h[row] -> LDS; issue h[col] gather into registers ----
  const int se = tid >> 2;             // 0..127 (edge)
  const int sq = tid & 3;              // quarter of the 128-col row
  {
    const int base = rowb[se]*HH;
    #pragma unroll
    for (int u = 0; u < 4; u++) {
      const int c = sq*8 + u*32;
      const int o = se*128 + (c ^ ((se&7)<<3));
      *(bf16x8*)&Ah[o] = *(const bf16x8*)&hbi[base + c];
      *(bf16x8*)&Al[o] = *(const bf16x8*)&hlo[base + c];
    }
  }
  bf16x8 pch[4], pcl[4];               // col-gather prefetch (T14 issue-early)
  {
    const int base = colb[se]*HH;
    #pragma unroll
    for (int u = 0; u < 4; u++) {
      const int c = sq*8 + u*32;
      pch[u] = *(const bf16x8*)&hbi[base + c];
      pcl[u] = *(const bf16x8*)&hlo[base + c];
    }
  }
  __syncthreads();                     // 2

  // ---- phase 3: GEMM1a (h_row @ W1[0:128]) — col gather in flight ----
  f32x4 acc[2][4];
  #pragma unroll
  for (int fr = 0; fr < 2; fr++)
    #pragma unroll
    for (int cf = 0; cf < 4; cf++) acc[fr][cf] = (f32x4){0,0,0,0};
  gemm24(Ah, Al, W1a_h, W1a_l, cl, g, eg, cg, acc);
  __syncthreads();                     // 3

  // ---- phase 4: write prefetched col tile -> LDS ----
  {
    #pragma unroll
    for (int u = 0; u < 4; u++) {
      const int c = sq*8 + u*32;
      const int o = se*128 + (c ^ ((se&7)<<3));
      *(bf16x8*)&Ah[o] = pch[u];
      *(bf16x8*)&Al[o] = pcl[u];
    }
  }
  __syncthreads();                     // 4

  // ---- phase 5: GEMM1b (h_col @ W1[128:256]) + radial/bias/silu epilogue ----
  gemm24(Ah, Al, W1b_h, W1b_l, cl, g, eg, cg, acc);
  {
    #pragma unroll
    for (int cf = 0; cf < 4; cf++) {
      const int c = cg*64 + cf*16 + cl;
      const float w256 = W1[(size_t)(2*HH)*HH + c];
      const float bb   = b1[c];
      #pragma unroll
      for (int fr = 0; fr < 2; fr++) {
        #pragma unroll
        for (int j = 0; j < 4; j++) {
          const int r = eg*32 + fr*16 + g*4 + j;
          acc[fr][cf][j] = silu_f(fmaf(radb[r], w256, acc[fr][cf][j]) + bb);
        }
      }
    }
  }
  __syncthreads();                     // 5 (all GEMM1 reads done)

  // ---- phase 6: store m1 -> Ah/Al ----
  #pragma unroll
  for (int fr = 0; fr < 2; fr++) {
    #pragma unroll
    for (int cf = 0; cf < 4; cf++) {
      #pragma unroll
      for (int j = 0; j < 4; j++) {
        const int r = eg*32 + fr*16 + g*4 + j;
        const int c = cg*64 + cf*16 + cl;
        const int sw = (r&7)<<3;
        const float v = acc[fr][cf][j];
        const short h0 = f2bf(v);
        Ah[r*128 + (c ^ sw)] = h0;
        Al[r*128 + (c ^ sw)] = f2bf(v - bf2f(h0));
      }
    }
  }
  __syncthreads();                     // 6

  // ---- phase 7: GEMM2 (m1 @ W2) + bias/silu + attention partial dot ----
  f32x4 m2[2][4];
  #pragma unroll
  for (int fr = 0; fr < 2; fr++)
    #pragma unroll
    for (int cf = 0; cf < 4; cf++) m2[fr][cf] = (f32x4){0,0,0,0};
  gemm24(Ah, Al, W2_h, W2_l, cl, g, eg, cg, m2);
  {
    float bbv[4], awv[4];
    #pragma unroll
    for (int cf = 0; cf < 4; cf++) {
      const int c = cg*64 + cf*16 + cl;
      bbv[cf] = b2[c]; awv[cf] = attw[c];
    }
    #pragma unroll
    for (int fr = 0; fr < 2; fr++) {
      #pragma unroll
      for (int j = 0; j < 4; j++) {
        float p = 0.f;
        #pragma unroll
        for (int cf = 0; cf < 4; cf++) {
          m2[fr][cf][j] = silu_f(m2[fr][cf][j] + bbv[cf]);
          p = fmaf(m2[fr][cf][j], awv[cf], p);
        }
        p += __shfl_xor(p, 1); p += __shfl_xor(p, 2);
        p += __shfl_xor(p, 4); p += __shfl_xor(p, 8);
        if (cl == 0) red[cg][eg*32 + fr*16 + g*4 + j] = p;
      }
    }
  }
  __syncthreads();                     // 7

  // ---- phase 8: attention scalar ----
  if (tid < EPB)
    scal[tid] = sigm_f(red[0][tid] + red[1][tid] + attb[0]);
  __syncthreads();                     // 8

  // ---- phase 9: gate, scatter m to mbuf, restage m for coord GEMM ----
  #pragma unroll
  for (int fr = 0; fr < 2; fr++) {
    #pragma unroll
    for (int cf = 0; cf < 4; cf++) {
      #pragma unroll
      for (int j = 0; j < 4; j++) {
        const int r = eg*32 + fr*16 + g*4 + j;
        const int c = cg*64 + cf*16 + cl;
        const float v = m2[fr][cf][j] * scal[r];
        if (SC) {
          mbuf[(size_t)posb[r]*HH + c] = v;
        } else {
          atomicAdd(&mbuf[(size_t)rowb[r]*HH + c], v);
        }
        const int sw = (r&7)<<3;
        const short h0 = f2bf(v);
        Ah[r*128 + (c ^ sw)] = h0;
        Al[r*128 + (c ^ sw)] = f2bf(v - bf2f(h0));
      }
    }
  }
  __syncthreads();                     // 9

  // ---- phase 10: GEMM3 (coord layer1, silu) + dot with cw2 ----
  f32x4 a3[2][4];
  #pragma unroll
  for (int fr = 0; fr < 2; fr++)
    #pragma unroll
    for (int cf = 0; cf < 4; cf++) a3[fr][cf] = (f32x4){0,0,0,0};
  gemm24(Ah, Al, C1_h, C1_l, cl, g, eg, cg, a3);
  {
    float bbv[4], c2v[4];
    #pragma unroll
    for (int cf = 0; cf < 4; cf++) {
      const int c = cg*64 + cf*16 + cl;
      bbv[cf] = cb1[c]; c2v[cf] = cw2[c];
    }
    #pragma unroll
    for (int fr = 0; fr < 2; fr++) {
      #pragma unroll
      for (int j = 0; j < 4; j++) {
        float p = 0.f;
        #pragma unroll
        for (int cf = 0; cf < 4; cf++)
          p = fmaf(silu_f(a3[fr][cf][j] + bbv[cf]), c2v[cf], p);
        p += __shfl_xor(p, 1); p += __shfl_xor(p, 2);
        p += __shfl_xor(p, 4); p += __shfl_xor(p, 8);
        if (cl == 0) red[cg][eg*32 + fr*16 + g*4 + j] = p;
      }
    }
  }
  __syncthreads();                     // 10

  // ---- coordinate aggregation ----
  if (tid < EPB) {
    const float cwv = red[0][tid] + red[1][tid];
    const int r = rowb[tid];
    atomicAdd(&aggx[r*3+0], diffb[tid][0]*cwv);
    atomicAdd(&aggx[r*3+1], diffb[tid][1]*cwv);
    atomicAdd(&aggx[r*3+2], diffb[tid][2]*cwv);
  }
}

// ---------------- fused node update ----------------
__device__ __forceinline__ void gemm_accum(const float (*buf)[132], const float* __restrict__ W,
                                           int c, int eo, float acc[32])
{
  for (int k0 = 0; k0 < HH; k0 += 4) {
    const float w0 = W[(k0+0)*HH + c];
    const float w1 = W[(k0+1)*HH + c];
    const float w2 = W[(k0+2)*HH + c];
    const float w3 = W[(k0+3)*HH + c];
    #pragma unroll
    for (int i = 0; i < 32; i++) {
      const float4 a = *(const float4*)&buf[eo*32+i][k0];
      acc[i] = fmaf(a.x, w0, fmaf(a.y, w1, fmaf(a.z, w2, fmaf(a.w, w3, acc[i]))));
    }
  }
}

template<bool SC>
__global__ __launch_bounds__(256, 2)
void k_node(float* __restrict__ hbuf, float* __restrict__ xbuf,
            const float* __restrict__ mbuf, const int* __restrict__ offs,
            const float* __restrict__ aggx,
            const float* __restrict__ W1, const float* __restrict__ b1,
            const float* __restrict__ W2, const float* __restrict__ b2,
            short* __restrict__ hbi, short* __restrict__ hlo)
{
  __shared__ float bufA[64][132];
  __shared__ float bufB[64][132];
  const int tid = threadIdx.x;
  const int c   = tid & (HH-1);
  const int no  = tid >> 7;
  const int nb  = blockIdx.x * 64;

  #pragma unroll
  for (int i = 0; i < 32; i++) {
    const int v = nb + no*32 + i;
    bufA[no*32+i][c] = (v < NN) ? hbuf[(size_t)v*HH + c] : 0.f;
  }
  __syncthreads();

  float acc[32];
  #pragma unroll
  for (int i = 0; i < 32; i++) acc[i] = 0.f;
  gemm_accum(bufA, W1, c, no, acc);
  __syncthreads();

  for (int i = 0; i < 32; i++) {
    const int v = nb + no*32 + i;
    float s = 0.f;
    if (v < NN) {
      if (SC) {
        const int beg = offs[v], end = offs[v+1];
        for (int j = beg; j < end; j++) s += mbuf[(size_t)j*HH + c];
      } else {
        s = mbuf[(size_t)v*HH + c];
      }
    }
    bufA[no*32+i][c] = s;
  }
  __syncthreads();
  gemm_accum(bufA, W1 + HH*HH, c, no, acc);
  {
    const float bb = b1[c];
    #pragma unroll
    for (int i = 0; i < 32; i++) bufB[no*32+i][c] = silu_f(acc[i] + bb);
  }
  __syncthreads();

  #pragma unroll
  for (int i = 0; i < 32; i++) acc[i] = 0.f;
  gemm_accum(bufB, W2, c, no, acc);
  {
    const float bb = b2[c];
    #pragma unroll
    for (int i = 0; i < 32; i++) {
      const int v = nb + no*32 + i;
      if (v < NN) {
        const float hn = hbuf[(size_t)v*HH + c] + acc[i] + bb;
        hbuf[(size_t)v*HH + c] = hn;
        const short hh = f2bf(hn);
        hbi[(size_t)v*HH + c] = hh;
        hlo[(size_t)v*HH + c] = f2bf(hn - bf2f(hh));
      }
    }
  }

  if (tid < 64) {
    const int v = nb + tid;
    if (v < NN) {
      const float ct = fmaxf((float)(offs[v+1] - offs[v]), 1.f);
      xbuf[v*3+0] += aggx[v*3+0] / ct;
      xbuf[v*3+1] += aggx[v*3+1] / ct;
      xbuf[v*3+2] += aggx[v*3+2] / ct;
    }
  }
}

// ---------------- mean pool ----------------
__global__ __launch_bounds__(128)
void k_pool(const float* __restrict__ h, float* __restrict__ g)
{
  const int c  = threadIdx.x;
  const int v0 = blockIdx.x * 100;
  float s = 0.f;
  for (int v = v0; v < v0 + 100; ++v) s += h[(size_t)v*HH + c];
  atomicAdd(&g[c], s);
}

// ---------------- out-embed (folded through mean) + head MLP ----------------
__global__ __launch_bounds__(128)
void k_head(const float* __restrict__ g,
            const float* __restrict__ eow, const float* __restrict__ eob,
            const float* __restrict__ hw1, const float* __restrict__ hb1,
            const float* __restrict__ hw2, const float* __restrict__ hb2,
            float* __restrict__ out)
{
  __shared__ float gm[HH], ho[HH], t1[HH];
  const int c = threadIdx.x;
  gm[c] = g[c] * (1.f / (float)NN);
  __syncthreads();
  float a = eob[c];
  for (int k = 0; k < HH; k++) a = fmaf(gm[k], eow[k*HH + c], a);
  ho[c] = a;
  __syncthreads();
  float t = hb1[c];
  for (int k = 0; k < HH; k++) t = fmaf(ho[k], hw1[k*HH + c], t);
  t1[c] = fmaxf(t, 0.f);
  __syncthreads();
  if (c < NOUT) {
    float o = hb2[c];
    for (int k = 0; k < HH; k++) o = fmaf(t1[k], hw2[k*NOUT + c], o);
    out[c] = o;
  }
}

extern "C" void kernel_launch(void* const* d_in, const int* in_sizes, int n_in,
                              void* d_out, int out_size, void* d_ws, size_t ws_size,
                              hipStream_t stream)
{
  const float* in_h  = (const float*)d_in[0];
  const float* in_x  = (const float*)d_in[1];
  const int*   edges = (const int*)  d_in[2];
  const float* eiw   = (const float*)d_in[3];
  const float* eib   = (const float*)d_in[4];
  const float* eow   = (const float*)d_in[5];
  const float* eob   = (const float*)d_in[6];
  const float* ew1   = (const float*)d_in[7];
  const float* eb1   = (const float*)d_in[8];
  const float* ew2   = (const float*)d_in[9];
  const float* eb2   = (const float*)d_in[10];
  const float* attw  = (const float*)d_in[11];
  const float* attb  = (const float*)d_in[12];
  const float* cw1   = (const float*)d_in[13];
  const float* cb1   = (const float*)d_in[14];
  const float* cw2   = (const float*)d_in[15];
  const float* nw1   = (const float*)d_in[16];
  const float* nb1   = (const float*)d_in[17];
  const float* nw2   = (const float*)d_in[18];
  const float* nb2   = (const float*)d_in[19];
  const float* hw1   = (const float*)d_in[20];
  const float* hb1   = (const float*)d_in[21];
  const float* hw2   = (const float*)d_in[22];
  const float* hb2   = (const float*)d_in[23];

  const int* row = edges;
  const int* col = edges + EE;

  // workspace layout (256B aligned slots)
  char* p = (char*)d_ws;
  auto alloc = [&](size_t bytes) { char* r = p; p += (bytes + 255) & ~(size_t)255; return r; };
  float* h    = (float*)alloc((size_t)NN*HH*4);
  float* x    = (float*)alloc((size_t)NN*3*4);
  float* aggx = (float*)alloc((size_t)NN*3*4);
  float* g    = (float*)alloc(HH*4);
  int*   deg  = (int*)  alloc((size_t)NN*4);
  int*   offs = (int*)  alloc((size_t)(NN+1)*4);
  int*   curs = (int*)  alloc((size_t)NN*4);
  int*   pos  = (int*)  alloc((size_t)EE*4);
  short* hbi  = (short*)alloc((size_t)NN*HH*2);
  short* hlo  = (short*)alloc((size_t)NN*HH*2);
  short* wph  = (short*)alloc((size_t)16*HH*HH*2);
  short* wpl  = (short*)alloc((size_t)16*HH*HH*2);
  const size_t baseUsed = (size_t)(p - (char*)d_ws);
  const bool sc = (ws_size >= baseUsed + (size_t)EE*HH*4);
  float* mbuf = (float*)alloc(sc ? (size_t)EE*HH*4 : (size_t)NN*HH*4);

  k_prep<<<16, 256, 0, stream>>>(ew1, ew2, cw1, wph, wpl);
  k_embed<<<NN/2, 256, 0, stream>>>(in_h, in_x, eiw, eib, h, x, hbi, hlo);

  hipMemsetAsync(deg, 0, (size_t)NN*4, stream);
  k_count<<<(EE+255)/256, 256, 0, stream>>>(row, deg);
  k_scan<<<1, 1024, 0, stream>>>(deg, offs, curs);
  k_pos<<<(EE+255)/256, 256, 0, stream>>>(row, curs, pos);

  for (int l = 0; l < LL; l++) {
    hipMemsetAsync(aggx, 0, (size_t)NN*3*4, stream);
    if (!sc) hipMemsetAsync(mbuf, 0, (size_t)NN*HH*4, stream);
    if (sc) {
      k_edge<true><<<EE/EPB, ETHR, 0, stream>>>(hbi, hlo, x, row, col, pos,
          wph, wpl, l,
          ew1 + (size_t)l*(2*HH+1)*HH, eb1 + l*HH, eb2 + l*HH,
          attw + l*HH, attb + l, cb1 + l*HH, cw2 + l*HH,
          mbuf, aggx);
      k_node<true><<<(NN + 63)/64, 256, 0, stream>>>(h, x, mbuf, offs, aggx,
          nw1 + (size_t)l*(2*HH)*HH, nb1 + l*HH,
          nw2 + (size_t)l*HH*HH,     nb2 + l*HH, hbi, hlo);
    } else {
      k_edge<false><<<EE/EPB, ETHR, 0, stream>>>(hbi, hlo, x, row, col, pos,
          wph, wpl, l,
          ew1 + (size_t)l*(2*HH+1)*HH, eb1 + l*HH, eb2 + l*HH,
          attw + l*HH, attb + l, cb1 + l*HH, cw2 + l*HH,
          mbuf, aggx);
      k_node<false><<<(NN + 63)/64, 256, 0, stream>>>(h, x, mbuf, offs, aggx,
          nw1 + (size_t)l*(2*HH)*HH, nb1 + l*HH,
          nw2 + (size_t)l*HH*HH,     nb2 + l*HH, hbi, hlo);
    }
  }

  hipMemsetAsync(g, 0, HH*4, stream);
  k_pool<<<500, 128, 0, stream>>>(h, g);
  k_head<<<1, 128, 0, stream>>>(g, eow, eob, hw1, hb1, hw2, hb2, (float*)d_out);
}

// Round 12
// 3725.137 us; speedup vs baseline: 1.3243x; 1.3243x over previous
//
#include <hip/hip_runtime.h>
#include <hip/hip_bf16.h>

#define NN   50000
#define EE   800000
#define FIN  32
#define HH   128
#define LL   4
#define NOUT 20
#define EPB  64      // edges per k_edge block
#define ETHR 256     // threads per k_edge block (4 waves)

typedef __attribute__((ext_vector_type(8))) short bf16x8;
typedef __attribute__((ext_vector_type(4))) short short4v;
typedef __attribute__((ext_vector_type(4))) float f32x4;

__device__ __forceinline__ float silu_f(float v){ return v / (1.f + __expf(-v)); }
__device__ __forceinline__ float sigm_f(float v){ return 1.f / (1.f + __expf(-v)); }

__device__ __forceinline__ short f2bf(float v){
  union { float f; unsigned u; } a; a.f = v;
  unsigned r = a.u + 0x7fff + ((a.u >> 16) & 1);
  return (short)(r >> 16);
}
__device__ __forceinline__ float bf2f(short s){
  union { unsigned u; float f; } a; a.u = ((unsigned)(unsigned short)s) << 16;
  return a.f;
}

__device__ __forceinline__ f32x4 mfma16(bf16x8 a, bf16x8 b, f32x4 c){
  return __builtin_amdgcn_mfma_f32_16x16x32_bf16(a, b, c, 0, 0, 0);
}

// ---------------------------------------------------------------------------
// A staged in LDS as bf16 hi/lo, element (e,k) at short index e*128 + (k ^ ((e&7)<<3)).
// Weights pre-transposed fragment-major bf16 hi/lo: Wp[c*128 + k] = bf16(W[k][c]).
// Split-bf16 GEMM (3-term): acc += A@W via ah*wh + ah*wl + al*wh.
// Wave tiling (EPB=64, 4 waves): wave wv covers ALL 64 edges x 32 cols
// [wv*32, wv*32+32). acc[fr][cf]: row e = fr*16+(lane>>4)*4+j,
// col = wv*32+cf*16+(lane&15). A-rep 4x, W-rep 1x per block.
// ---------------------------------------------------------------------------
__device__ __forceinline__ void gemm42(const short* Ah, const short* Al,
                                       const short* __restrict__ Wh,
                                       const short* __restrict__ Wl,
                                       int cl, int g, int wc0, f32x4 acc[4][2])
{
  #pragma unroll
  for (int kb = 0; kb < 4; kb++) {
    const int kk = kb*32 + g*8;
    bf16x8 bh[2], bl[2];
    #pragma unroll
    for (int cf = 0; cf < 2; cf++) {
      const int wb = (wc0 + cf*16 + cl)*HH + kk;
      bh[cf] = *(const bf16x8*)&Wh[wb];
      bl[cf] = *(const bf16x8*)&Wl[wb];
    }
    #pragma unroll
    for (int fr = 0; fr < 4; fr++) {
      const int e = fr*16 + cl;
      const int off = e*128 + (kk ^ ((e&7)<<3));
      const bf16x8 ah = *(const bf16x8*)&Ah[off];
      const bf16x8 al = *(const bf16x8*)&Al[off];
      #pragma unroll
      for (int cf = 0; cf < 2; cf++) {
        acc[fr][cf] = mfma16(ah, bh[cf], acc[fr][cf]);
        acc[fr][cf] = mfma16(ah, bl[cf], acc[fr][cf]);
        acc[fr][cf] = mfma16(al, bh[cf], acc[fr][cf]);
      }
    }
  }
}

// ---------------- weight prep: fp32 -> transposed bf16 hi/lo planes ----------
__global__ __launch_bounds__(256)
void k_prep(const float* __restrict__ ew1, const float* __restrict__ ew2,
            const float* __restrict__ cw1v, short* __restrict__ wph,
            short* __restrict__ wpl)
{
  const int b = blockIdx.x;          // 0..15
  const int l = b >> 2, m = b & 3;
  const float* src = (m==0) ? ew1 + (size_t)l*(2*HH+1)*HH
                   : (m==1) ? ew1 + (size_t)l*(2*HH+1)*HH + HH*HH
                   : (m==2) ? ew2 + (size_t)l*HH*HH
                            : cw1v + (size_t)l*HH*HH;
  short* dh = wph + (size_t)b*HH*HH;
  short* dl = wpl + (size_t)b*HH*HH;
  for (int idx = threadIdx.x; idx < HH*HH; idx += 256) {
    const int k = idx >> 7, c = idx & 127;
    const float v = src[idx];
    const short hh = f2bf(v);
    dh[c*HH + k] = hh;
    dl[c*HH + k] = f2bf(v - bf2f(hh));
  }
}

// ---------------- input embedding + x copy + h planes ----------------
__global__ __launch_bounds__(256)
void k_embed(const float* __restrict__ hin, const float* __restrict__ xin,
             const float* __restrict__ W, const float* __restrict__ b,
             float* __restrict__ hout, float* __restrict__ xout,
             short* __restrict__ hbi, short* __restrict__ hlo)
{
  __shared__ float wl[FIN*HH];
  const int tid = threadIdx.x;
  for (int j = tid; j < FIN*HH; j += 256) wl[j] = W[j];
  __syncthreads();
  const int c  = tid & (HH-1);
  const int no = tid >> 7;
  const int v  = blockIdx.x * 2 + no;
  if (v < NN) {
    const float* hr = hin + (size_t)v * FIN;
    float acc = b[c];
    #pragma unroll
    for (int k = 0; k < FIN; k++) acc = fmaf(hr[k], wl[k*HH + c], acc);
    hout[(size_t)v*HH + c] = acc;
    const short hh = f2bf(acc);
    hbi[(size_t)v*HH + c] = hh;
    hlo[(size_t)v*HH + c] = f2bf(acc - bf2f(hh));
    if (c < 3) xout[v*3 + c] = xin[v*3 + c];
  }
}

// ---------------- degree count ----------------
__global__ __launch_bounds__(256)
void k_count(const int* __restrict__ row, int* __restrict__ deg)
{
  const int e = blockIdx.x * 256 + threadIdx.x;
  if (e < EE) atomicAdd(&deg[row[e]], 1);
}

// ---------------- single-block exclusive prefix scan over deg ----------------
__global__ __launch_bounds__(1024)
void k_scan(const int* __restrict__ deg, int* __restrict__ offs, int* __restrict__ cursor)
{
  __shared__ int part[1024];
  const int t = threadIdx.x;
  const int base = t * 49;
  int s = 0;
  for (int i = 0; i < 49; i++) { const int idx = base + i; s += (idx < NN) ? deg[idx] : 0; }
  part[t] = s;
  __syncthreads();
  if (t == 0) { int run = 0; for (int i = 0; i < 1024; i++) { const int v = part[i]; part[i] = run; run += v; } }
  __syncthreads();
  int run = part[t];
  for (int i = 0; i < 49; i++) {
    const int idx = base + i;
    if (idx < NN) { offs[idx] = run; cursor[idx] = run; run += deg[idx]; }
  }
  if (t == 1023) offs[NN] = EE;
}

// ---------------- per-edge slot assignment ----------------
__global__ __launch_bounds__(256)
void k_pos(const int* __restrict__ row, int* __restrict__ cursor, int* __restrict__ pos)
{
  const int e = blockIdx.x * 256 + threadIdx.x;
  if (e < EE) pos[e] = atomicAdd(&cursor[row[e]], 1);
}

// ---------------- fused edge pipeline: 64 edges, 4 waves x 32 cols ----------
template<bool SC>
__global__ __launch_bounds__(ETHR, 4)
void k_edge(const short* __restrict__ hbi, const short* __restrict__ hlo,
            const float* __restrict__ xbuf,
            const int* __restrict__ row, const int* __restrict__ col,
            const int* __restrict__ pos,
            const short* __restrict__ wph, const short* __restrict__ wpl, int lidx,
            const float* __restrict__ W1, const float* __restrict__ b1,
            const float* __restrict__ b2,
            const float* __restrict__ attw, const float* __restrict__ attb,
            const float* __restrict__ cb1, const float* __restrict__ cw2,
            float* __restrict__ mbuf, float* __restrict__ aggx)
{
  __shared__ short Ah[EPB*128];        // 16 KB
  __shared__ short Al[EPB*128];        // 16 KB
  __shared__ float red[4][EPB];        // 1 KB
  __shared__ float scal[EPB];
  __shared__ int   rowb[EPB];
  __shared__ int   colb[EPB];
  __shared__ int   posb[EPB];
  __shared__ float diffb[EPB][3];
  __shared__ float radb[EPB];

  const int tid  = threadIdx.x;
  const int lane = tid & 63;
  const int wv   = tid >> 6;           // 0..3
  const int cl   = lane & 15;
  const int g    = lane >> 4;
  const int wc0  = wv * 32;
  const int eb   = blockIdx.x * EPB;

  const short* W1a_h = wph + (size_t)(lidx*4+0)*HH*HH;
  const short* W1a_l = wpl + (size_t)(lidx*4+0)*HH*HH;
  const short* W1b_h = wph + (size_t)(lidx*4+1)*HH*HH;
  const short* W1b_l = wpl + (size_t)(lidx*4+1)*HH*HH;
  const short* W2_h  = wph + (size_t)(lidx*4+2)*HH*HH;
  const short* W2_l  = wpl + (size_t)(lidx*4+2)*HH*HH;
  const short* C1_h  = wph + (size_t)(lidx*4+3)*HH*HH;
  const short* C1_l  = wpl + (size_t)(lidx*4+3)*HH*HH;

  // ---- phase 1: edge metadata ----
  if (tid < EPB) {
    const int r  = row[eb + tid];
    const int c2 = col[eb + tid];
    rowb[tid] = r; colb[tid] = c2;
    if (SC) posb[tid] = pos[eb + tid];
    const float dx = xbuf[r*3+0] - xbuf[c2*3+0];
    const float dy = xbuf[r*3+1] - xbuf[c2*3+1];
    const float dz = xbuf[r*3+2] - xbuf[c2*3+2];
    diffb[tid][0] = dx; diffb[tid][1] = dy; diffb[tid][2] = dz;
    radb[tid] = dx*dx + dy*dy + dz*dz;
  }
  __syncthreads();                     // 1

  // ---- phase 2: stage h[row] -> LDS; issue h[col] gather into registers ----
  const int se = tid >> 2;             // 0..63 (edge)
  const int sq = tid & 3;              // quarter of the 128-col row
  {
    const int base = rowb[se]*HH;
    #pragma unroll
    for (int u = 0; u < 4; u++) {
      const int c = sq*8 + u*32;
      const int o = se*128 + (c ^ ((se&7)<<3));
      *(bf16x8*)&Ah[o] = *(const bf16x8*)&hbi[base + c];
      *(bf16x8*)&Al[o] = *(const bf16x8*)&hlo[base + c];
    }
  }
  bf16x8 pch[4], pcl[4];               // col-gather prefetch
  {
    const int base = colb[se]*HH;
    #pragma unroll
    for (int u = 0; u < 4; u++) {
      const int c = sq*8 + u*32;
      pch[u] = *(const bf16x8*)&hbi[base + c];
      pcl[u] = *(const bf16x8*)&hlo[base + c];
    }
  }
  __syncthreads();                     // 2

  // ---- phase 3: GEMM1a (h_row @ W1[0:128]) ----
  f32x4 acc[4][2];
  #pragma unroll
  for (int fr = 0; fr < 4; fr++)
    #pragma unroll
    for (int cf = 0; cf < 2; cf++) acc[fr][cf] = (f32x4){0,0,0,0};
  gemm42(Ah, Al, W1a_h, W1a_l, cl, g, wc0, acc);
  __syncthreads();                     // 3

  // ---- phase 4: write prefetched col tile -> LDS ----
  {
    #pragma unroll
    for (int u = 0; u < 4; u++) {
      const int c = sq*8 + u*32;
      const int o = se*128 + (c ^ ((se&7)<<3));
      *(bf16x8*)&Ah[o] = pch[u];
      *(bf16x8*)&Al[o] = pcl[u];
    }
  }
  __syncthreads();                     // 4

  // ---- phase 5: GEMM1b (h_col @ W1[128:256]) + radial/bias/silu epilogue ----
  gemm42(Ah, Al, W1b_h, W1b_l, cl, g, wc0, acc);
  {
    #pragma unroll
    for (int cf = 0; cf < 2; cf++) {
      const int c = wc0 + cf*16 + cl;
      const float w256 = W1[(size_t)(2*HH)*HH + c];
      const float bb   = b1[c];
      #pragma unroll
      for (int fr = 0; fr < 4; fr++) {
        #pragma unroll
        for (int j = 0; j < 4; j++) {
          const int r = fr*16 + g*4 + j;
          acc[fr][cf][j] = silu_f(fmaf(radb[r], w256, acc[fr][cf][j]) + bb);
        }
      }
    }
  }
  __syncthreads();                     // 5 (all GEMM1 reads done)

  // ---- phase 6: store m1 -> Ah/Al ----
  #pragma unroll
  for (int fr = 0; fr < 4; fr++) {
    #pragma unroll
    for (int cf = 0; cf < 2; cf++) {
      #pragma unroll
      for (int j = 0; j < 4; j++) {
        const int r = fr*16 + g*4 + j;
        const int c = wc0 + cf*16 + cl;
        const int sw = (r&7)<<3;
        const float v = acc[fr][cf][j];
        const short h0 = f2bf(v);
        Ah[r*128 + (c ^ sw)] = h0;
        Al[r*128 + (c ^ sw)] = f2bf(v - bf2f(h0));
      }
    }
  }
  __syncthreads();                     // 6

  // ---- phase 7: GEMM2 (m1 @ W2) + bias/silu + attention partial dot ----
  f32x4 m2[4][2];
  #pragma unroll
  for (int fr = 0; fr < 4; fr++)
    #pragma unroll
    for (int cf = 0; cf < 2; cf++) m2[fr][cf] = (f32x4){0,0,0,0};
  gemm42(Ah, Al, W2_h, W2_l, cl, g, wc0, m2);
  {
    const float bb0 = b2[wc0 + cl],      bb1 = b2[wc0 + 16 + cl];
    const float aw0 = attw[wc0 + cl],    aw1 = attw[wc0 + 16 + cl];
    #pragma unroll
    for (int fr = 0; fr < 4; fr++) {
      #pragma unroll
      for (int j = 0; j < 4; j++) {
        m2[fr][0][j] = silu_f(m2[fr][0][j] + bb0);
        m2[fr][1][j] = silu_f(m2[fr][1][j] + bb1);
        float p = fmaf(m2[fr][0][j], aw0, m2[fr][1][j]*aw1);
        p += __shfl_xor(p, 1); p += __shfl_xor(p, 2);
        p += __shfl_xor(p, 4); p += __shfl_xor(p, 8);
        if (cl == 0) red[wv][fr*16 + g*4 + j] = p;
      }
    }
  }
  __syncthreads();                     // 7

  // ---- phase 8: attention scalar ----
  if (tid < EPB)
    scal[tid] = sigm_f(red[0][tid] + red[1][tid] + red[2][tid] + red[3][tid] + attb[0]);
  __syncthreads();                     // 8

  // ---- phase 9: gate, scatter m to mbuf, restage m for coord GEMM ----
  #pragma unroll
  for (int fr = 0; fr < 4; fr++) {
    #pragma unroll
    for (int cf = 0; cf < 2; cf++) {
      #pragma unroll
      for (int j = 0; j < 4; j++) {
        const int r = fr*16 + g*4 + j;
        const int c = wc0 + cf*16 + cl;
        const float v = m2[fr][cf][j] * scal[r];
        if (SC) {
          mbuf[(size_t)posb[r]*HH + c] = v;
        } else {
          atomicAdd(&mbuf[(size_t)rowb[r]*HH + c], v);
        }
        const int sw = (r&7)<<3;
        const short h0 = f2bf(v);
        Ah[r*128 + (c ^ sw)] = h0;
        Al[r*128 + (c ^ sw)] = f2bf(v - bf2f(h0));
      }
    }
  }
  __syncthreads();                     // 9

  // ---- phase 10: GEMM3 (coord layer1, silu) + dot with cw2 ----
  f32x4 a3[4][2];
  #pragma unroll
  for (int fr = 0; fr < 4; fr++)
    #pragma unroll
    for (int cf = 0; cf < 2; cf++) a3[fr][cf] = (f32x4){0,0,0,0};
  gemm42(Ah, Al, C1_h, C1_l, cl, g, wc0, a3);
  {
    const float bb0 = cb1[wc0 + cl],  bb1 = cb1[wc0 + 16 + cl];
    const float c20 = cw2[wc0 + cl],  c21 = cw2[wc0 + 16 + cl];
    #pragma unroll
    for (int fr = 0; fr < 4; fr++) {
      #pragma unroll
      for (int j = 0; j < 4; j++) {
        float p = fmaf(silu_f(a3[fr][0][j] + bb0), c20,
                       silu_f(a3[fr][1][j] + bb1)*c21);
        p += __shfl_xor(p, 1); p += __shfl_xor(p, 2);
        p += __shfl_xor(p, 4); p += __shfl_xor(p, 8);
        if (cl == 0) red[wv][fr*16 + g*4 + j] = p;
      }
    }
  }
  __syncthreads();                     // 10

  // ---- coordinate aggregation ----
  if (tid < EPB) {
    const float cwv = red[0][tid] + red[1][tid] + red[2][tid] + red[3][tid];
    const int r = rowb[tid];
    atomicAdd(&aggx[r*3+0], diffb[tid][0]*cwv);
    atomicAdd(&aggx[r*3+1], diffb[tid][1]*cwv);
    atomicAdd(&aggx[r*3+2], diffb[tid][2]*cwv);
  }
}

// ---------------- fused node update ----------------
__device__ __forceinline__ void gemm_accum(const float (*buf)[132], const float* __restrict__ W,
                                           int c, int eo, float acc[32])
{
  for (int k0 = 0; k0 < HH; k0 += 4) {
    const float w0 = W[(k0+0)*HH + c];
    const float w1 = W[(k0+1)*HH + c];
    const float w2 = W[(k0+2)*HH + c];
    const float w3 = W[(k0+3)*HH + c];
    #pragma unroll
    for (int i = 0; i < 32; i++) {
      const float4 a = *(const float4*)&buf[eo*32+i][k0];
      acc[i] = fmaf(a.x, w0, fmaf(a.y, w1, fmaf(a.z, w2, fmaf(a.w, w3, acc[i]))));
    }
  }
}

template<bool SC>
__global__ __launch_bounds__(256, 2)
void k_node(float* __restrict__ hbuf, float* __restrict__ xbuf,
            const float* __restrict__ mbuf, const int* __restrict__ offs,
            const float* __restrict__ aggx,
            const float* __restrict__ W1, const float* __restrict__ b1,
            const float* __restrict__ W2, const float* __restrict__ b2,
            short* __restrict__ hbi, short* __restrict__ hlo)
{
  __shared__ float bufA[64][132];
  __shared__ float bufB[64][132];
  const int tid = threadIdx.x;
  const int c   = tid & (HH-1);
  const int no  = tid >> 7;
  const int nb  = blockIdx.x * 64;

  #pragma unroll
  for (int i = 0; i < 32; i++) {
    const int v = nb + no*32 + i;
    bufA[no*32+i][c] = (v < NN) ? hbuf[(size_t)v*HH + c] : 0.f;
  }
  __syncthreads();

  float acc[32];
  #pragma unroll
  for (int i = 0; i < 32; i++) acc[i] = 0.f;
  gemm_accum(bufA, W1, c, no, acc);
  __syncthreads();

  for (int i = 0; i < 32; i++) {
    const int v = nb + no*32 + i;
    float s = 0.f;
    if (v < NN) {
      if (SC) {
        const int beg = offs[v], end = offs[v+1];
        for (int j = beg; j < end; j++) s += mbuf[(size_t)j*HH + c];
      } else {
        s = mbuf[(size_t)v*HH + c];
      }
    }
    bufA[no*32+i][c] = s;
  }
  __syncthreads();
  gemm_accum(bufA, W1 + HH*HH, c, no, acc);
  {
    const float bb = b1[c];
    #pragma unroll
    for (int i = 0; i < 32; i++) bufB[no*32+i][c] = silu_f(acc[i] + bb);
  }
  __syncthreads();

  #pragma unroll
  for (int i = 0; i < 32; i++) acc[i] = 0.f;
  gemm_accum(bufB, W2, c, no, acc);
  {
    const float bb = b2[c];
    #pragma unroll
    for (int i = 0; i < 32; i++) {
      const int v = nb + no*32 + i;
      if (v < NN) {
        const float hn = hbuf[(size_t)v*HH + c] + acc[i] + bb;
        hbuf[(size_t)v*HH + c] = hn;
        const short hh = f2bf(hn);
        hbi[(size_t)v*HH + c] = hh;
        hlo[(size_t)v*HH + c] = f2bf(hn - bf2f(hh));
      }
    }
  }

  if (tid < 64) {
    const int v = nb + tid;
    if (v < NN) {
      const float ct = fmaxf((float)(offs[v+1] - offs[v]), 1.f);
      xbuf[v*3+0] += aggx[v*3+0] / ct;
      xbuf[v*3+1] += aggx[v*3+1] / ct;
      xbuf[v*3+2] += aggx[v*3+2] / ct;
    }
  }
}

// ---------------- mean pool ----------------
__global__ __launch_bounds__(128)
void k_pool(const float* __restrict__ h, float* __restrict__ g)
{
  const int c  = threadIdx.x;
  const int v0 = blockIdx.x * 100;
  float s = 0.f;
  for (int v = v0; v < v0 + 100; ++v) s += h[(size_t)v*HH + c];
  atomicAdd(&g[c], s);
}

// ---------------- out-embed (folded through mean) + head MLP ----------------
__global__ __launch_bounds__(128)
void k_head(const float* __restrict__ g,
            const float* __restrict__ eow, const float* __restrict__ eob,
            const float* __restrict__ hw1, const float* __restrict__ hb1,
            const float* __restrict__ hw2, const float* __restrict__ hb2,
            float* __restrict__ out)
{
  __shared__ float gm[HH], ho[HH], t1[HH];
  const int c = threadIdx.x;
  gm[c] = g[c] * (1.f / (float)NN);
  __syncthreads();
  float a = eob[c];
  for (int k = 0; k < HH; k++) a = fmaf(gm[k], eow[k*HH + c], a);
  ho[c] = a;
  __syncthreads();
  float t = hb1[c];
  for (int k = 0; k < HH; k++) t = fmaf(ho[k], hw1[k*HH + c], t);
  t1[c] = fmaxf(t, 0.f);
  __syncthreads();
  if (c < NOUT) {
    float o = hb2[c];
    for (int k = 0; k < HH; k++) o = fmaf(t1[k], hw2[k*NOUT + c], o);
    out[c] = o;
  }
}

extern "C" void kernel_launch(void* const* d_in, const int* in_sizes, int n_in,
                              void* d_out, int out_size, void* d_ws, size_t ws_size,
                              hipStream_t stream)
{
  const float* in_h  = (const float*)d_in[0];
  const float* in_x  = (const float*)d_in[1];
  const int*   edges = (const int*)  d_in[2];
  const float* eiw   = (const float*)d_in[3];
  const float* eib   = (const float*)d_in[4];
  const float* eow   = (const float*)d_in[5];
  const float* eob   = (const float*)d_in[6];
  const float* ew1   = (const float*)d_in[7];
  const float* eb1   = (const float*)d_in[8];
  const float* ew2   = (const float*)d_in[9];
  const float* eb2   = (const float*)d_in[10];
  const float* attw  = (const float*)d_in[11];
  const float* attb  = (const float*)d_in[12];
  const float* cw1   = (const float*)d_in[13];
  const float* cb1   = (const float*)d_in[14];
  const float* cw2   = (const float*)d_in[15];
  const float* nw1   = (const float*)d_in[16];
  const float* nb1   = (const float*)d_in[17];
  const float* nw2   = (const float*)d_in[18];
  const float* nb2   = (const float*)d_in[19];
  const float* hw1   = (const float*)d_in[20];
  const float* hb1   = (const float*)d_in[21];
  const float* hw2   = (const float*)d_in[22];
  const float* hb2   = (const float*)d_in[23];

  const int* row = edges;
  const int* col = edges + EE;

  // workspace layout (256B aligned slots)
  char* p = (char*)d_ws;
  auto alloc = [&](size_t bytes) { char* r = p; p += (bytes + 255) & ~(size_t)255; return r; };
  float* h    = (float*)alloc((size_t)NN*HH*4);
  float* x    = (float*)alloc((size_t)NN*3*4);
  float* aggx = (float*)alloc((size_t)NN*3*4);
  float* g    = (float*)alloc(HH*4);
  int*   deg  = (int*)  alloc((size_t)NN*4);
  int*   offs = (int*)  alloc((size_t)(NN+1)*4);
  int*   curs = (int*)  alloc((size_t)NN*4);
  int*   pos  = (int*)  alloc((size_t)EE*4);
  short* hbi  = (short*)alloc((size_t)NN*HH*2);
  short* hlo  = (short*)alloc((size_t)NN*HH*2);
  short* wph  = (short*)alloc((size_t)16*HH*HH*2);
  short* wpl  = (short*)alloc((size_t)16*HH*HH*2);
  const size_t baseUsed = (size_t)(p - (char*)d_ws);
  const bool sc = (ws_size >= baseUsed + (size_t)EE*HH*4);
  float* mbuf = (float*)alloc(sc ? (size_t)EE*HH*4 : (size_t)NN*HH*4);

  k_prep<<<16, 256, 0, stream>>>(ew1, ew2, cw1, wph, wpl);
  k_embed<<<NN/2, 256, 0, stream>>>(in_h, in_x, eiw, eib, h, x, hbi, hlo);

  hipMemsetAsync(deg, 0, (size_t)NN*4, stream);
  k_count<<<(EE+255)/256, 256, 0, stream>>>(row, deg);
  k_scan<<<1, 1024, 0, stream>>>(deg, offs, curs);
  k_pos<<<(EE+255)/256, 256, 0, stream>>>(row, curs, pos);

  for (int l = 0; l < LL; l++) {
    hipMemsetAsync(aggx, 0, (size_t)NN*3*4, stream);
    if (!sc) hipMemsetAsync(mbuf, 0, (size_t)NN*HH*4, stream);
    if (sc) {
      k_edge<true><<<EE/EPB, ETHR, 0, stream>>>(hbi, hlo, x, row, col, pos,
          wph, wpl, l,
          ew1 + (size_t)l*(2*HH+1)*HH, eb1 + l*HH, eb2 + l*HH,
          attw + l*HH, attb + l, cb1 + l*HH, cw2 + l*HH,
          mbuf, aggx);
      k_node<true><<<(NN + 63)/64, 256, 0, stream>>>(h, x, mbuf, offs, aggx,
          nw1 + (size_t)l*(2*HH)*HH, nb1 + l*HH,
          nw2 + (size_t)l*HH*HH,     nb2 + l*HH, hbi, hlo);
    } else {
      k_edge<false><<<EE/EPB, ETHR, 0, stream>>>(hbi, hlo, x, row, col, pos,
          wph, wpl, l,
          ew1 + (size_t)l*(2*HH+1)*HH, eb1 + l*HH, eb2 + l*HH,
          attw + l*HH, attb + l, cb1 + l*HH, cw2 + l*HH,
          mbuf, aggx);
      k_node<false><<<(NN + 63)/64, 256, 0, stream>>>(h, x, mbuf, offs, aggx,
          nw1 + (size_t)l*(2*HH)*HH, nb1 + l*HH,
          nw2 + (size_t)l*HH*HH,     nb2 + l*HH, hbi, hlo);
    }
  }

  hipMemsetAsync(g, 0, HH*4, stream);
  k_pool<<<500, 128, 0, stream>>>(h, g);
  k_head<<<1, 128, 0, stream>>>(g, eow, eob, hw1, hb1, hw2, hb2, (float*)d_out);
}